// Round 4
// baseline (938.456 us; speedup 1.0000x reference)
//
#include <hip/hip_runtime.h>

#define HDIM 128
#define SCAN_CHUNK 1024
#define NB 8      // dst-range buckets (one per XCD)
#define NS 32     // shards per bucket (atomic spreading)

// ---------- degree histogram ----------
__global__ void deg_kernel(const int* __restrict__ src, const int* __restrict__ dst,
                           int* __restrict__ deg_out, int* __restrict__ deg_in, int E) {
    int e = blockIdx.x * blockDim.x + threadIdx.x;
    if (e < E) {
        atomicAdd(&deg_out[src[e]], 1);
        atomicAdd(&deg_in[dst[e]], 1);
    }
}

// ---------- inverse-sqrt degree ----------
__global__ void inv_kernel(const int* __restrict__ deg_out, const int* __restrict__ deg_in,
                           float* __restrict__ inv_out, float* __restrict__ inv_in, int N) {
    int n = blockIdx.x * blockDim.x + threadIdx.x;
    if (n < N) {
        float dO = (float)(deg_out[n] > 1 ? deg_out[n] : 1);
        float dI = (float)(deg_in[n]  > 1 ? deg_in[n]  : 1);
        inv_out[n] = 1.0f / sqrtf(dO);
        inv_in[n]  = 1.0f / sqrtf(dI);
    }
}

// ---------- hierarchical scan pass 1: per-block sums ----------
__global__ __launch_bounds__(1024) void scan_blk_sum(const int* __restrict__ deg,
                                                     int* __restrict__ blk_sum, int n) {
    __shared__ int red[1024];
    int tid = threadIdx.x;
    int i = blockIdx.x * SCAN_CHUNK + tid;
    red[tid] = (i < n) ? deg[i] : 0;
    __syncthreads();
    for (int s = 512; s > 0; s >>= 1) {
        if (tid < s) red[tid] += red[tid + s];
        __syncthreads();
    }
    if (tid == 0) blk_sum[blockIdx.x] = red[0];
}

// ---------- hierarchical scan pass 2: exclusive scan of block sums (nblk <= 128) ----------
__global__ __launch_bounds__(128) void scan_blk_off(const int* __restrict__ blk_sum,
                                                    int* __restrict__ blk_off, int nblk) {
    __shared__ int buf[128];
    int tid = threadIdx.x;
    int v = (tid < nblk) ? blk_sum[tid] : 0;
    buf[tid] = v;
    __syncthreads();
    for (int offset = 1; offset < 128; offset <<= 1) {
        int t = (tid >= offset) ? buf[tid - offset] : 0;
        __syncthreads();
        buf[tid] += t;
        __syncthreads();
    }
    if (tid < nblk) blk_off[tid] = buf[tid] - v;   // exclusive
}

// ---------- hierarchical scan pass 3: per-block inclusive scan + offset ----------
__global__ __launch_bounds__(1024) void scan_apply(const int* __restrict__ deg,
                                                   const int* __restrict__ blk_off,
                                                   int* __restrict__ row_ptr,
                                                   int* __restrict__ pos, int n) {
    __shared__ int buf[1024];
    int tid = threadIdx.x;
    int i = blockIdx.x * SCAN_CHUNK + tid;
    int v = (i < n) ? deg[i] : 0;
    buf[tid] = v;
    __syncthreads();
    for (int offset = 1; offset < 1024; offset <<= 1) {
        int t = (tid >= offset) ? buf[tid - offset] : 0;
        __syncthreads();
        buf[tid] += t;
        __syncthreads();
    }
    int base = blk_off[blockIdx.x];
    if (i < n) {
        int incl = base + buf[tid];
        row_ptr[i + 1] = incl;
        pos[i] = incl - v;
    }
    if (i == 0) row_ptr[0] = 0;
}

// ---------- old single-pass scatter fill (fallback if ws too small) ----------
__global__ void fill_kernel(const int* __restrict__ src, const int* __restrict__ dst,
                            int* __restrict__ pos, int* __restrict__ csr_src, int E) {
    int e = blockIdx.x * blockDim.x + threadIdx.x;
    if (e < E) {
        int d = dst[e];
        int idx = atomicAdd(&pos[d], 1);
        csr_src[idx] = src[e];
    }
}

// ---------- binned fill phase A: wave-coalesced bucket append ----------
__global__ __launch_bounds__(256) void bucket_kernel(
        const int* __restrict__ src, const int* __restrict__ dst,
        int* __restrict__ cnt, int2* __restrict__ buckets,
        int E, int N, int cap) {
    int e = blockIdx.x * 256 + threadIdx.x;
    int lane = threadIdx.x & 63;
    int shard = blockIdx.x & (NS - 1);
    int b = NB;            // inactive sentinel
    int s = 0, d = 0;
    if (e < E) {
        s = src[e];
        d = dst[e];
        b = (int)(((long long)d * NB) / N);   // exact dst-range bucket, 0..NB-1
    }
    unsigned long long lt = (lane == 63) ? 0x7fffffffffffffffull : ((1ull << lane) - 1ull);
    for (int bi = 0; bi < NB; ++bi) {
        unsigned long long mask = __ballot(b == bi);
        if (mask == 0ull) continue;
        if (b == bi) {
            int rank = __popcll(mask & lt);
            int leader = __ffsll((unsigned long long)mask) - 1;
            int base = 0;
            if (lane == leader)
                base = atomicAdd(&cnt[bi * NS + shard], (int)__popcll(mask));
            base = __shfl(base, leader, 64);
            int idx = base + rank;
            if (idx < cap)
                buckets[(size_t)(bi * NS + shard) * cap + idx] = make_int2(s, d);
        }
    }
}

// ---------- binned fill phase B: per-bucket scatter (XCD-local window) ----------
// blockIdx % 8 == bucket -> round-robin block->XCD mapping keeps each bucket's
// pos/csr window resident in one XCD's L2 (perf heuristic only).
__global__ __launch_bounds__(256) void fill_binned_kernel(
        const int* __restrict__ cnt, const int2* __restrict__ buckets,
        int* __restrict__ pos, int* __restrict__ csr_src, int cap) {
    int blk = blockIdx.x;
    int b = blk & (NB - 1);
    int shard = (blk >> 3) & (NS - 1);
    int chunk = blk >> 8;
    int r = b * NS + shard;
    int n = cnt[r];
    int i = chunk * 256 + threadIdx.x;
    if (i < n) {
        int2 sd = buckets[(size_t)r * cap + i];
        int slot = atomicAdd(&pos[sd.y], 1);
        csr_src[slot] = sd.x;
    }
}

// ---------- embedding gather, pre-scaled: x[n] = z_table[z[n]] * inv_out[n] ----------
__global__ void embed_kernel(const int* __restrict__ z, const float* __restrict__ z_table,
                             const float* __restrict__ inv_out,
                             float* __restrict__ x, int N) {
    int t = blockIdx.x * blockDim.x + threadIdx.x;
    int n = t >> 5;          // 32 float4 per row (H=128)
    int c = t & 31;
    if (n < N) {
        int zz = z[n];
        float w = inv_out[n];
        float4 v = reinterpret_cast<const float4*>(z_table)[(size_t)zz * 32 + c];
        v.x *= w; v.y *= w; v.z *= w; v.w *= w;
        reinterpret_cast<float4*>(x)[(size_t)n * 32 + c] = v;
    }
}

// ---------- pull-based GraphConv, 8-way unrolled ----------
// input xs is PRE-SCALED by inv_out. mode 0: out = relu(acc*inv_in+b)*inv_out
//                                    mode 1: out = acc*inv_in+b (final layer)
__global__ __launch_bounds__(256) void conv_kernel(
        const float* __restrict__ xs, float* __restrict__ out,
        const int* __restrict__ row_ptr, const int* __restrict__ csr_src,
        const float* __restrict__ inv_out, const float* __restrict__ inv_in,
        const float* __restrict__ bias, int N, int mode) {
    int gtid = blockIdx.x * blockDim.x + threadIdx.x;
    int n = gtid >> 6;       // wave per node
    int lane = threadIdx.x & 63;
    if (n >= N) return;

    int start = row_ptr[n];
    int end   = row_ptr[n + 1];

    float2 a0 = make_float2(0.f, 0.f), a1 = a0, a2 = a0, a3 = a0;
    float2 a4 = a0, a5 = a0, a6 = a0, a7 = a0;
    int e = start;
    for (; e + 8 <= end; e += 8) {
        int s0 = csr_src[e + 0], s1 = csr_src[e + 1];
        int s2 = csr_src[e + 2], s3 = csr_src[e + 3];
        int s4 = csr_src[e + 4], s5 = csr_src[e + 5];
        int s6 = csr_src[e + 6], s7 = csr_src[e + 7];
        float2 v0 = reinterpret_cast<const float2*>(xs + (size_t)s0 * HDIM)[lane];
        float2 v1 = reinterpret_cast<const float2*>(xs + (size_t)s1 * HDIM)[lane];
        float2 v2 = reinterpret_cast<const float2*>(xs + (size_t)s2 * HDIM)[lane];
        float2 v3 = reinterpret_cast<const float2*>(xs + (size_t)s3 * HDIM)[lane];
        float2 v4 = reinterpret_cast<const float2*>(xs + (size_t)s4 * HDIM)[lane];
        float2 v5 = reinterpret_cast<const float2*>(xs + (size_t)s5 * HDIM)[lane];
        float2 v6 = reinterpret_cast<const float2*>(xs + (size_t)s6 * HDIM)[lane];
        float2 v7 = reinterpret_cast<const float2*>(xs + (size_t)s7 * HDIM)[lane];
        a0.x += v0.x; a0.y += v0.y;  a1.x += v1.x; a1.y += v1.y;
        a2.x += v2.x; a2.y += v2.y;  a3.x += v3.x; a3.y += v3.y;
        a4.x += v4.x; a4.y += v4.y;  a5.x += v5.x; a5.y += v5.y;
        a6.x += v6.x; a6.y += v6.y;  a7.x += v7.x; a7.y += v7.y;
    }
    if (e + 4 <= end) {
        int s0 = csr_src[e + 0], s1 = csr_src[e + 1];
        int s2 = csr_src[e + 2], s3 = csr_src[e + 3];
        float2 v0 = reinterpret_cast<const float2*>(xs + (size_t)s0 * HDIM)[lane];
        float2 v1 = reinterpret_cast<const float2*>(xs + (size_t)s1 * HDIM)[lane];
        float2 v2 = reinterpret_cast<const float2*>(xs + (size_t)s2 * HDIM)[lane];
        float2 v3 = reinterpret_cast<const float2*>(xs + (size_t)s3 * HDIM)[lane];
        a0.x += v0.x; a0.y += v0.y;  a1.x += v1.x; a1.y += v1.y;
        a2.x += v2.x; a2.y += v2.y;  a3.x += v3.x; a3.y += v3.y;
        e += 4;
    }
    for (; e < end; ++e) {
        int s = csr_src[e];
        float2 v = reinterpret_cast<const float2*>(xs + (size_t)s * HDIM)[lane];
        a0.x += v.x; a0.y += v.y;
    }
    float2 acc;
    acc.x = ((a0.x + a1.x) + (a2.x + a3.x)) + ((a4.x + a5.x) + (a6.x + a7.x));
    acc.y = ((a0.y + a1.y) + (a2.y + a3.y)) + ((a4.y + a5.y) + (a6.y + a7.y));

    float win = inv_in[n];
    float2 b = reinterpret_cast<const float2*>(bias)[lane];
    float2 o;
    o.x = acc.x * win + b.x;
    o.y = acc.y * win + b.y;
    if (mode == 0) {
        float wout = inv_out[n];
        o.x = fmaxf(o.x, 0.0f) * wout;
        o.y = fmaxf(o.y, 0.0f) * wout;
    }
    reinterpret_cast<float2*>(out + (size_t)n * HDIM)[lane] = o;
}

// ---------- center pooling + 2-layer MLP: one block (128 thr) per pair ----------
__global__ __launch_bounds__(128) void mlp_kernel(
        const float* __restrict__ x, const int* __restrict__ pairs,
        const float* __restrict__ W1, const float* __restrict__ b1,
        const float* __restrict__ W2, const float* __restrict__ b2,
        float* __restrict__ out, int B) {
    __shared__ float xp[HDIM];
    __shared__ float red[HDIM];
    int p = blockIdx.x;
    int t = threadIdx.x;
    int a = pairs[p];
    int bnode = pairs[B + p];
    xp[t] = x[(size_t)a * HDIM + t] * x[(size_t)bnode * HDIM + t];
    __syncthreads();
    float h = b1[t];
    #pragma unroll 8
    for (int k = 0; k < HDIM; ++k) h += xp[k] * W1[k * HDIM + t];
    h = fmaxf(h, 0.0f);
    red[t] = h * W2[t];
    __syncthreads();
    for (int s = 64; s > 0; s >>= 1) {
        if (t < s) red[t] += red[t + s];
        __syncthreads();
    }
    if (t == 0) out[p] = red[0] + b2[0];
}

extern "C" void kernel_launch(void* const* d_in, const int* in_sizes, int n_in,
                              void* d_out, int out_size, void* d_ws, size_t ws_size,
                              hipStream_t stream) {
    const int*   z       = (const int*)d_in[0];
    const int*   src     = (const int*)d_in[1];
    const int*   dst     = (const int*)d_in[2];
    const int*   pairs   = (const int*)d_in[3];
    const float* z_table = (const float*)d_in[4];
    const float* bias[3] = {(const float*)d_in[5], (const float*)d_in[6], (const float*)d_in[7]};
    const float* W1      = (const float*)d_in[8];
    const float* b1      = (const float*)d_in[9];
    const float* W2      = (const float*)d_in[10];
    const float* b2      = (const float*)d_in[11];

    const int N = in_sizes[0];
    const int E = in_sizes[1];
    const int B = in_sizes[3] / 2;
    const int nblk = (N + SCAN_CHUNK - 1) / SCAN_CHUNK;

    char* ws = (char*)d_ws;
    size_t off = 0;
    auto carve = [&](size_t bytes) -> void* {
        void* p = ws + off;
        off = (off + bytes + 255) & ~(size_t)255;
        return p;
    };
    int*   deg_out = (int*)carve((size_t)N * 4);
    int*   deg_in  = (int*)carve((size_t)N * 4);
    float* inv_out = (float*)carve((size_t)N * 4);
    float* inv_in  = (float*)carve((size_t)N * 4);
    int*   row_ptr = (int*)carve((size_t)(N + 1) * 4);
    int*   pos     = (int*)carve((size_t)N * 4);
    int*   blk_sum = (int*)carve((size_t)nblk * 4);
    int*   blk_off = (int*)carve((size_t)nblk * 4);
    int*   csr_src = (int*)carve((size_t)E * 4);
    float* xb      = (float*)carve((size_t)N * HDIM * 4);
    float* mb      = (float*)carve((size_t)N * HDIM * 4);

    // binned-fill extras (appended so base layout is unchanged)
    const int nreg = NB * NS;
    const int mean = (E + nreg - 1) / nreg;
    const int cap = (int)((((size_t)mean * 2) + 255) / 256) * 256;   // 2x headroom, mult of 256
    const int chunks = cap / 256;
    int*  bucket_cnt = (int*)carve((size_t)nreg * 4);
    int2* buckets    = (int2*)carve((size_t)nreg * (size_t)cap * 8);
    bool use_binned = (off <= ws_size);

    hipMemsetAsync(deg_out, 0, (size_t)N * 4, stream);
    hipMemsetAsync(deg_in,  0, (size_t)N * 4, stream);

    deg_kernel<<<(E + 255) / 256, 256, 0, stream>>>(src, dst, deg_out, deg_in, E);
    inv_kernel<<<(N + 255) / 256, 256, 0, stream>>>(deg_out, deg_in, inv_out, inv_in, N);

    scan_blk_sum<<<nblk, 1024, 0, stream>>>(deg_in, blk_sum, N);
    scan_blk_off<<<1, 128, 0, stream>>>(blk_sum, blk_off, nblk);
    scan_apply<<<nblk, 1024, 0, stream>>>(deg_in, blk_off, row_ptr, pos, N);

    if (use_binned) {
        hipMemsetAsync(bucket_cnt, 0, (size_t)nreg * 4, stream);
        bucket_kernel<<<(E + 255) / 256, 256, 0, stream>>>(src, dst, bucket_cnt, buckets, E, N, cap);
        fill_binned_kernel<<<nreg * chunks, 256, 0, stream>>>(bucket_cnt, buckets, pos, csr_src, cap);
    } else {
        fill_kernel<<<(E + 255) / 256, 256, 0, stream>>>(src, dst, pos, csr_src, E);
    }

    embed_kernel<<<((size_t)N * 32 + 255) / 256, 256, 0, stream>>>(z, z_table, inv_out, xb, N);

    float* cur = xb;
    float* nxt = mb;
    for (int layer = 0; layer < 3; ++layer) {
        int mode = (layer < 2) ? 0 : 1;
        long long threads = (long long)N * 64;
        conv_kernel<<<(threads + 255) / 256, 256, 0, stream>>>(
            cur, nxt, row_ptr, csr_src, inv_out, inv_in, bias[layer], N, mode);
        float* tmp = cur; cur = nxt; nxt = tmp;
    }

    mlp_kernel<<<B, 128, 0, stream>>>(cur, pairs, W1, b1, W2, b2, (float*)d_out, B);
}

// Round 5
// 627.161 us; speedup vs baseline: 1.4964x; 1.4964x over previous
//
#include <hip/hip_runtime.h>

#define HDIM 128
#define SCAN_CHUNK 1024

// ---------- degree histogram ----------
__global__ void deg_kernel(const int* __restrict__ src, const int* __restrict__ dst,
                           int* __restrict__ deg_out, int* __restrict__ deg_in, int E) {
    int e = blockIdx.x * blockDim.x + threadIdx.x;
    if (e < E) {
        atomicAdd(&deg_out[src[e]], 1);
        atomicAdd(&deg_in[dst[e]], 1);
    }
}

// ---------- inverse-sqrt degree ----------
__global__ void inv_kernel(const int* __restrict__ deg_out, const int* __restrict__ deg_in,
                           float* __restrict__ inv_out, float* __restrict__ inv_in, int N) {
    int n = blockIdx.x * blockDim.x + threadIdx.x;
    if (n < N) {
        float dO = (float)(deg_out[n] > 1 ? deg_out[n] : 1);
        float dI = (float)(deg_in[n]  > 1 ? deg_in[n]  : 1);
        inv_out[n] = 1.0f / sqrtf(dO);
        inv_in[n]  = 1.0f / sqrtf(dI);
    }
}

// ---------- hierarchical scan pass 1: per-block sums ----------
__global__ __launch_bounds__(1024) void scan_blk_sum(const int* __restrict__ deg,
                                                     int* __restrict__ blk_sum, int n) {
    __shared__ int red[1024];
    int tid = threadIdx.x;
    int i = blockIdx.x * SCAN_CHUNK + tid;
    red[tid] = (i < n) ? deg[i] : 0;
    __syncthreads();
    for (int s = 512; s > 0; s >>= 1) {
        if (tid < s) red[tid] += red[tid + s];
        __syncthreads();
    }
    if (tid == 0) blk_sum[blockIdx.x] = red[0];
}

// ---------- hierarchical scan pass 2: exclusive scan of block sums (nblk <= 128) ----------
__global__ __launch_bounds__(128) void scan_blk_off(const int* __restrict__ blk_sum,
                                                    int* __restrict__ blk_off, int nblk) {
    __shared__ int buf[128];
    int tid = threadIdx.x;
    int v = (tid < nblk) ? blk_sum[tid] : 0;
    buf[tid] = v;
    __syncthreads();
    for (int offset = 1; offset < 128; offset <<= 1) {
        int t = (tid >= offset) ? buf[tid - offset] : 0;
        __syncthreads();
        buf[tid] += t;
        __syncthreads();
    }
    if (tid < nblk) blk_off[tid] = buf[tid] - v;   // exclusive
}

// ---------- hierarchical scan pass 3: per-block inclusive scan + offset ----------
__global__ __launch_bounds__(1024) void scan_apply(const int* __restrict__ deg,
                                                   const int* __restrict__ blk_off,
                                                   int* __restrict__ row_ptr,
                                                   int* __restrict__ pos, int n) {
    __shared__ int buf[1024];
    int tid = threadIdx.x;
    int i = blockIdx.x * SCAN_CHUNK + tid;
    int v = (i < n) ? deg[i] : 0;
    buf[tid] = v;
    __syncthreads();
    for (int offset = 1; offset < 1024; offset <<= 1) {
        int t = (tid >= offset) ? buf[tid - offset] : 0;
        __syncthreads();
        buf[tid] += t;
        __syncthreads();
    }
    int base = blk_off[blockIdx.x];
    if (i < n) {
        int incl = base + buf[tid];
        row_ptr[i + 1] = incl;
        pos[i] = incl - v;
    }
    if (i == 0) row_ptr[0] = 0;
}

// ---------- scatter edges into CSR (grouped by dst) ----------
__global__ void fill_kernel(const int* __restrict__ src, const int* __restrict__ dst,
                            int* __restrict__ pos, int* __restrict__ csr_src, int E) {
    int e = blockIdx.x * blockDim.x + threadIdx.x;
    if (e < E) {
        int d = dst[e];
        int idx = atomicAdd(&pos[d], 1);
        csr_src[idx] = src[e];
    }
}

// ---------- embedding gather, pre-scaled: x[n] = z_table[z[n]] * inv_out[n] ----------
__global__ void embed_kernel(const int* __restrict__ z, const float* __restrict__ z_table,
                             const float* __restrict__ inv_out,
                             float* __restrict__ x, int N) {
    int t = blockIdx.x * blockDim.x + threadIdx.x;
    int n = t >> 5;          // 32 float4 per row (H=128)
    int c = t & 31;
    if (n < N) {
        int zz = z[n];
        float w = inv_out[n];
        float4 v = reinterpret_cast<const float4*>(z_table)[(size_t)zz * 32 + c];
        v.x *= w; v.y *= w; v.z *= w; v.w *= w;
        reinterpret_cast<float4*>(x)[(size_t)n * 32 + c] = v;
    }
}

// ---------- pull-based GraphConv, 8-way unrolled, 2 waves/block ----------
// input xs is PRE-SCALED by inv_out. mode 0: out = relu(acc*inv_in+b)*inv_out
//                                    mode 1: out = acc*inv_in+b (final layer)
__global__ __launch_bounds__(128) void conv_kernel(
        const float* __restrict__ xs, float* __restrict__ out,
        const int* __restrict__ row_ptr, const int* __restrict__ csr_src,
        const float* __restrict__ inv_out, const float* __restrict__ inv_in,
        const float* __restrict__ bias, int N, int mode) {
    int gtid = blockIdx.x * blockDim.x + threadIdx.x;
    int n = gtid >> 6;       // wave per node
    int lane = threadIdx.x & 63;
    if (n >= N) return;

    int start = row_ptr[n];
    int end   = row_ptr[n + 1];

    float2 a0 = make_float2(0.f, 0.f), a1 = a0, a2 = a0, a3 = a0;
    float2 a4 = a0, a5 = a0, a6 = a0, a7 = a0;
    int e = start;
    for (; e + 8 <= end; e += 8) {
        int s0 = csr_src[e + 0], s1 = csr_src[e + 1];
        int s2 = csr_src[e + 2], s3 = csr_src[e + 3];
        int s4 = csr_src[e + 4], s5 = csr_src[e + 5];
        int s6 = csr_src[e + 6], s7 = csr_src[e + 7];
        float2 v0 = reinterpret_cast<const float2*>(xs + (size_t)s0 * HDIM)[lane];
        float2 v1 = reinterpret_cast<const float2*>(xs + (size_t)s1 * HDIM)[lane];
        float2 v2 = reinterpret_cast<const float2*>(xs + (size_t)s2 * HDIM)[lane];
        float2 v3 = reinterpret_cast<const float2*>(xs + (size_t)s3 * HDIM)[lane];
        float2 v4 = reinterpret_cast<const float2*>(xs + (size_t)s4 * HDIM)[lane];
        float2 v5 = reinterpret_cast<const float2*>(xs + (size_t)s5 * HDIM)[lane];
        float2 v6 = reinterpret_cast<const float2*>(xs + (size_t)s6 * HDIM)[lane];
        float2 v7 = reinterpret_cast<const float2*>(xs + (size_t)s7 * HDIM)[lane];
        a0.x += v0.x; a0.y += v0.y;  a1.x += v1.x; a1.y += v1.y;
        a2.x += v2.x; a2.y += v2.y;  a3.x += v3.x; a3.y += v3.y;
        a4.x += v4.x; a4.y += v4.y;  a5.x += v5.x; a5.y += v5.y;
        a6.x += v6.x; a6.y += v6.y;  a7.x += v7.x; a7.y += v7.y;
    }
    if (e + 4 <= end) {
        int s0 = csr_src[e + 0], s1 = csr_src[e + 1];
        int s2 = csr_src[e + 2], s3 = csr_src[e + 3];
        float2 v0 = reinterpret_cast<const float2*>(xs + (size_t)s0 * HDIM)[lane];
        float2 v1 = reinterpret_cast<const float2*>(xs + (size_t)s1 * HDIM)[lane];
        float2 v2 = reinterpret_cast<const float2*>(xs + (size_t)s2 * HDIM)[lane];
        float2 v3 = reinterpret_cast<const float2*>(xs + (size_t)s3 * HDIM)[lane];
        a0.x += v0.x; a0.y += v0.y;  a1.x += v1.x; a1.y += v1.y;
        a2.x += v2.x; a2.y += v2.y;  a3.x += v3.x; a3.y += v3.y;
        e += 4;
    }
    for (; e < end; ++e) {
        int s = csr_src[e];
        float2 v = reinterpret_cast<const float2*>(xs + (size_t)s * HDIM)[lane];
        a0.x += v.x; a0.y += v.y;
    }
    float2 acc;
    acc.x = ((a0.x + a1.x) + (a2.x + a3.x)) + ((a4.x + a5.x) + (a6.x + a7.x));
    acc.y = ((a0.y + a1.y) + (a2.y + a3.y)) + ((a4.y + a5.y) + (a6.y + a7.y));

    float win = inv_in[n];
    float2 b = reinterpret_cast<const float2*>(bias)[lane];
    float2 o;
    o.x = acc.x * win + b.x;
    o.y = acc.y * win + b.y;
    if (mode == 0) {
        float wout = inv_out[n];
        o.x = fmaxf(o.x, 0.0f) * wout;
        o.y = fmaxf(o.y, 0.0f) * wout;
    }
    reinterpret_cast<float2*>(out + (size_t)n * HDIM)[lane] = o;
}

// ---------- center pooling + 2-layer MLP: one block (128 thr) per pair ----------
__global__ __launch_bounds__(128) void mlp_kernel(
        const float* __restrict__ x, const int* __restrict__ pairs,
        const float* __restrict__ W1, const float* __restrict__ b1,
        const float* __restrict__ W2, const float* __restrict__ b2,
        float* __restrict__ out, int B) {
    __shared__ float xp[HDIM];
    __shared__ float red[HDIM];
    int p = blockIdx.x;
    int t = threadIdx.x;
    int a = pairs[p];
    int bnode = pairs[B + p];
    xp[t] = x[(size_t)a * HDIM + t] * x[(size_t)bnode * HDIM + t];
    __syncthreads();
    float h = b1[t];
    #pragma unroll 8
    for (int k = 0; k < HDIM; ++k) h += xp[k] * W1[k * HDIM + t];
    h = fmaxf(h, 0.0f);
    red[t] = h * W2[t];
    __syncthreads();
    for (int s = 64; s > 0; s >>= 1) {
        if (t < s) red[t] += red[t + s];
        __syncthreads();
    }
    if (t == 0) out[p] = red[0] + b2[0];
}

extern "C" void kernel_launch(void* const* d_in, const int* in_sizes, int n_in,
                              void* d_out, int out_size, void* d_ws, size_t ws_size,
                              hipStream_t stream) {
    const int*   z       = (const int*)d_in[0];
    const int*   src     = (const int*)d_in[1];
    const int*   dst     = (const int*)d_in[2];
    const int*   pairs   = (const int*)d_in[3];
    const float* z_table = (const float*)d_in[4];
    const float* bias[3] = {(const float*)d_in[5], (const float*)d_in[6], (const float*)d_in[7]};
    const float* W1      = (const float*)d_in[8];
    const float* b1      = (const float*)d_in[9];
    const float* W2      = (const float*)d_in[10];
    const float* b2      = (const float*)d_in[11];

    const int N = in_sizes[0];
    const int E = in_sizes[1];
    const int B = in_sizes[3] / 2;
    const int nblk = (N + SCAN_CHUNK - 1) / SCAN_CHUNK;

    char* ws = (char*)d_ws;
    size_t off = 0;
    auto carve = [&](size_t bytes) -> void* {
        void* p = ws + off;
        off = (off + bytes + 255) & ~(size_t)255;
        return p;
    };
    int*   deg_out = (int*)carve((size_t)N * 4);
    int*   deg_in  = (int*)carve((size_t)N * 4);
    float* inv_out = (float*)carve((size_t)N * 4);
    float* inv_in  = (float*)carve((size_t)N * 4);
    int*   row_ptr = (int*)carve((size_t)(N + 1) * 4);
    int*   pos     = (int*)carve((size_t)N * 4);
    int*   blk_sum = (int*)carve((size_t)nblk * 4);
    int*   blk_off = (int*)carve((size_t)nblk * 4);
    int*   csr_src = (int*)carve((size_t)E * 4);
    float* xb      = (float*)carve((size_t)N * HDIM * 4);
    float* mb      = (float*)carve((size_t)N * HDIM * 4);

    hipMemsetAsync(deg_out, 0, (size_t)N * 4, stream);
    hipMemsetAsync(deg_in,  0, (size_t)N * 4, stream);

    deg_kernel<<<(E + 255) / 256, 256, 0, stream>>>(src, dst, deg_out, deg_in, E);
    inv_kernel<<<(N + 255) / 256, 256, 0, stream>>>(deg_out, deg_in, inv_out, inv_in, N);

    scan_blk_sum<<<nblk, 1024, 0, stream>>>(deg_in, blk_sum, N);
    scan_blk_off<<<1, 128, 0, stream>>>(blk_sum, blk_off, nblk);
    scan_apply<<<nblk, 1024, 0, stream>>>(deg_in, blk_off, row_ptr, pos, N);

    fill_kernel<<<(E + 255) / 256, 256, 0, stream>>>(src, dst, pos, csr_src, E);
    embed_kernel<<<((size_t)N * 32 + 255) / 256, 256, 0, stream>>>(z, z_table, inv_out, xb, N);

    float* cur = xb;
    float* nxt = mb;
    for (int layer = 0; layer < 3; ++layer) {
        int mode = (layer < 2) ? 0 : 1;
        long long threads = (long long)N * 64;
        conv_kernel<<<(threads + 127) / 128, 128, 0, stream>>>(
            cur, nxt, row_ptr, csr_src, inv_out, inv_in, bias[layer], N, mode);
        float* tmp = cur; cur = nxt; nxt = tmp;
    }

    mlp_kernel<<<B, 128, 0, stream>>>(cur, pairs, W1, b1, W2, b2, (float*)d_out, B);
}